// Round 2
// baseline (647.144 us; speedup 1.0000x reference)
//
#include <hip/hip_runtime.h>
#include <hip/hip_bf16.h>

#define NDIM_IN 128
#define HID 64

// ---------------------------------------------------------------------------
// Degree count (in-degree by dst; self-loop handled as +1 later)
// ---------------------------------------------------------------------------
__global__ __launch_bounds__(256) void count_deg(const int* __restrict__ dst,
                                                 int* __restrict__ cnt, int E) {
  int i = blockIdx.x * 256 + threadIdx.x;
  if (i < E) atomicAdd(&cnt[dst[i]], 1);
}

__global__ __launch_bounds__(256) void make_dinv(const int* __restrict__ cnt,
                                                 float* __restrict__ dinv, int n) {
  int i = blockIdx.x * 256 + threadIdx.x;
  if (i < n) dinv[i] = rsqrtf((float)cnt[i] + 1.0f);  // +1 = self loop; deg>=1 always
}

// ---------------------------------------------------------------------------
// Exclusive scan of cnt -> rowptr (3-kernel hierarchical scan, n <= 512*256)
// ---------------------------------------------------------------------------
__global__ __launch_bounds__(256) void scan1(const int* __restrict__ cnt,
                                             int* __restrict__ rp,
                                             int* __restrict__ bs, int n) {
  __shared__ int s[256];
  int t = threadIdx.x;
  int i = blockIdx.x * 256 + t;
  int v = (i < n) ? cnt[i] : 0;
  s[t] = v;
  __syncthreads();
  for (int off = 1; off < 256; off <<= 1) {
    int x = (t >= off) ? s[t - off] : 0;
    __syncthreads();
    s[t] += x;
    __syncthreads();
  }
  if (i < n) rp[i] = s[t] - v;          // exclusive within block
  if (t == 255) bs[blockIdx.x] = s[255];
}

__global__ __launch_bounds__(512) void scan2(int* __restrict__ bs, int nb) {
  __shared__ int s[512];
  int t = threadIdx.x;
  int v = (t < nb) ? bs[t] : 0;
  s[t] = v;
  __syncthreads();
  for (int off = 1; off < 512; off <<= 1) {
    int x = (t >= off) ? s[t - off] : 0;
    __syncthreads();
    s[t] += x;
    __syncthreads();
  }
  if (t < nb) bs[t] = s[t] - v;         // exclusive block offsets
}

__global__ __launch_bounds__(256) void scan3(int* __restrict__ rp,
                                             const int* __restrict__ boff,
                                             int* __restrict__ pos, int n, int E) {
  int i = blockIdx.x * 256 + threadIdx.x;
  if (i < n) {
    int v = rp[i] + boff[blockIdx.x];
    rp[i] = v;
    pos[i] = v;                          // running fill cursor starts at rowptr
  }
  if (i == 0) rp[n] = E;
}

// ---------------------------------------------------------------------------
// CSR fill: col[p]=src only (edge weight folded into dinv scaling — see gemm
// epilogue + spmm epilogue). 4 independent edges per thread for ILP to hide
// the atomic-return round trip.
// ---------------------------------------------------------------------------
__global__ __launch_bounds__(256) void fill_csr(const int* __restrict__ src,
                                                const int* __restrict__ dst,
                                                int* __restrict__ pos,
                                                int* __restrict__ col, int E) {
  int tid = blockIdx.x * 256 + threadIdx.x;
  int nthreads = gridDim.x * 256;
#pragma unroll 4
  for (int k = 0; k < 4; k++) {
    int i = tid + k * nthreads;
    if (i < E) {
      int s = src[i];
      int d = dst[i];
      int p = atomicAdd(&pos[d], 1);
      col[p] = s;
    }
  }
}

// ---------------------------------------------------------------------------
// Dense transform T' = (X @ W) * dinv[row]  (K in {64,128}), thread-per-node
// dinv fold: msg(s->d) = T[s]*dinv[s]*dinv[d]  =>  agg[d] = dinv[d]*Σ T'[col]
// ---------------------------------------------------------------------------
template <int K>
__global__ __launch_bounds__(256) void gemm_xw(const float* __restrict__ X,
                                               const float* __restrict__ W,
                                               const float* __restrict__ dinv,
                                               float* __restrict__ T, int n) {
  __shared__ float Ws[K * 64];
  for (int i = threadIdx.x; i < K * 64; i += 256) Ws[i] = W[i];
  __syncthreads();
  int node = blockIdx.x * 256 + threadIdx.x;
  if (node >= n) return;
  float4 acc[16];
#pragma unroll
  for (int j = 0; j < 16; j++) acc[j] = make_float4(0.f, 0.f, 0.f, 0.f);
  const float4* __restrict__ xr = (const float4*)(X + (size_t)node * K);
#pragma unroll
  for (int kc = 0; kc < K / 4; kc++) {
    float4 xv = xr[kc];
    float xs[4] = {xv.x, xv.y, xv.z, xv.w};
#pragma unroll
    for (int kk = 0; kk < 4; kk++) {
      float xk = xs[kk];
      const float4* wr = (const float4*)(Ws + (kc * 4 + kk) * 64);
#pragma unroll
      for (int j = 0; j < 16; j++) {
        float4 w = wr[j];
        acc[j].x += xk * w.x;
        acc[j].y += xk * w.y;
        acc[j].z += xk * w.z;
        acc[j].w += xk * w.w;
      }
    }
  }
  float di = dinv[node];
  float4* __restrict__ o = (float4*)(T + (size_t)node * 64);
#pragma unroll
  for (int j = 0; j < 16; j++) {
    acc[j].x *= di; acc[j].y *= di; acc[j].z *= di; acc[j].w *= di;
    o[j] = acc[j];
  }
}

// ---------------------------------------------------------------------------
// SpMM gather: H[v] = relu( dinv[v] * ( T'[v] + Σ_{e in CSR(v)} T'[col[e]] )
//                           + bias )
// wave-per-node, lane = feature (HID==64==wavefront)
// ---------------------------------------------------------------------------
__global__ __launch_bounds__(256) void spmm_relu(const int* __restrict__ rp,
                                                 const int* __restrict__ col,
                                                 const float* __restrict__ T,
                                                 const float* __restrict__ dinv,
                                                 const float* __restrict__ bias,
                                                 float* __restrict__ H, int n) {
  int gid = blockIdx.x * 256 + threadIdx.x;
  int v = gid >> 6;
  int lane = gid & 63;
  if (v >= n) return;
  int beg = rp[v], end = rp[v + 1];
  float acc0 = T[(size_t)v * HID + lane];  // self loop (dinv[v] applied at end)
  float acc1 = 0.f, acc2 = 0.f, acc3 = 0.f;
  int e = beg;
  for (; e + 4 <= end; e += 4) {
    int s0 = col[e], s1 = col[e + 1], s2 = col[e + 2], s3 = col[e + 3];
    acc0 += T[(size_t)s0 * HID + lane];
    acc1 += T[(size_t)s1 * HID + lane];
    acc2 += T[(size_t)s2 * HID + lane];
    acc3 += T[(size_t)s3 * HID + lane];
  }
  for (; e < end; e++) acc0 += T[(size_t)col[e] * HID + lane];
  float r = dinv[v] * (acc0 + acc1 + acc2 + acc3) + bias[lane];
  H[(size_t)v * HID + lane] = r > 0.f ? r : 0.f;
}

// ---------------------------------------------------------------------------
// Fused MLP head: out = relu(H @ Wp1 + bp1) @ Wp2 + bp2, thread-per-node
// ---------------------------------------------------------------------------
__global__ __launch_bounds__(256) void mlp_head(const float* __restrict__ H,
                                                const float* __restrict__ Wp1,
                                                const float* __restrict__ bp1,
                                                const float* __restrict__ Wp2,
                                                const float* __restrict__ bp2,
                                                float* __restrict__ out, int n) {
  __shared__ float W1t[32 * 64];  // transposed: W1t[j*64+k] = Wp1[k*32+j]
  __shared__ float w2s[32];
  __shared__ float b1s[32];
  for (int i = threadIdx.x; i < 64 * 32; i += 256) {
    int k = i >> 5, j = i & 31;
    W1t[j * 64 + k] = Wp1[i];
  }
  if (threadIdx.x < 32) {
    w2s[threadIdx.x] = Wp2[threadIdx.x];
    b1s[threadIdx.x] = bp1[threadIdx.x];
  }
  __syncthreads();
  int node = blockIdx.x * 256 + threadIdx.x;
  if (node >= n) return;
  float4 h[16];
  const float4* __restrict__ hr = (const float4*)(H + (size_t)node * 64);
#pragma unroll
  for (int j = 0; j < 16; j++) h[j] = hr[j];
  float o = bp2[0];
#pragma unroll
  for (int j = 0; j < 32; j++) {
    const float4* wr = (const float4*)(W1t + j * 64);
    float4 a4 = make_float4(0.f, 0.f, 0.f, 0.f);
#pragma unroll
    for (int k = 0; k < 16; k++) {
      float4 w = wr[k];
      a4.x += h[k].x * w.x;
      a4.y += h[k].y * w.y;
      a4.z += h[k].z * w.z;
      a4.w += h[k].w * w.w;
    }
    float a = a4.x + a4.y + a4.z + a4.w + b1s[j];
    a = a > 0.f ? a : 0.f;
    o += a * w2s[j];
  }
  out[node] = o;
}

// ---------------------------------------------------------------------------
extern "C" void kernel_launch(void* const* d_in, const int* in_sizes, int n_in,
                              void* d_out, int out_size, void* d_ws, size_t ws_size,
                              hipStream_t stream) {
  const float* x   = (const float*)d_in[0];
  const int* edge  = (const int*)d_in[1];
  const float* W1  = (const float*)d_in[3];
  const float* b1  = (const float*)d_in[4];
  const float* W2  = (const float*)d_in[5];
  const float* b2  = (const float*)d_in[6];
  const float* W3  = (const float*)d_in[7];
  const float* b3  = (const float*)d_in[8];
  const float* Wp1 = (const float*)d_in[9];
  const float* bp1 = (const float*)d_in[10];
  const float* Wp2 = (const float*)d_in[11];
  const float* bp2 = (const float*)d_in[12];
  float* out = (float*)d_out;

  const int n = in_sizes[0] / NDIM_IN;   // 100000
  const int E = in_sizes[1] / 2;         // 1600000
  const int* src = edge;
  const int* dst = edge + E;

  // workspace carve-out (256B aligned slices)
  char* ws = (char*)d_ws;
  size_t off = 0;
  auto carve = [&](size_t bytes) {
    char* p = ws + off;
    off = (off + bytes + 255) & ~(size_t)255;
    return p;
  };
  int*   cnt   = (int*)carve((size_t)n * 4);
  float* dinv  = (float*)carve((size_t)n * 4);
  int*   rp    = (int*)carve(((size_t)n + 1) * 4);
  int*   pos   = (int*)carve((size_t)n * 4);
  int*   bsum  = (int*)carve(512 * 4);
  int*   col   = (int*)carve((size_t)E * 4);
  float* bufT  = (float*)carve((size_t)n * HID * 4);
  float* bufA  = (float*)carve((size_t)n * HID * 4);
  (void)ws_size; (void)n_in; (void)out_size;

  const int nbN = (n + 255) / 256;       // 391 (<=512 for scan2)
  const int nbE = (E + 255) / 256;
  const int nbE4 = (E / 4 + 255) / 256;  // fill_csr: 4 edges/thread

  hipMemsetAsync(cnt, 0, (size_t)n * 4, stream);
  count_deg<<<nbE, 256, 0, stream>>>(dst, cnt, E);
  make_dinv<<<nbN, 256, 0, stream>>>(cnt, dinv, n);
  scan1<<<nbN, 256, 0, stream>>>(cnt, rp, bsum, n);
  scan2<<<1, 512, 0, stream>>>(bsum, nbN);
  scan3<<<nbN, 256, 0, stream>>>(rp, bsum, pos, n, E);
  fill_csr<<<nbE4, 256, 0, stream>>>(src, dst, pos, col, E);

  const int nbSp = ((n * 64) + 255) / 256;

  // layer 1: 128 -> 64
  gemm_xw<128><<<nbN, 256, 0, stream>>>(x, W1, dinv, bufT, n);
  spmm_relu<<<nbSp, 256, 0, stream>>>(rp, col, bufT, dinv, b1, bufA, n);
  // layer 2: 64 -> 64
  gemm_xw<64><<<nbN, 256, 0, stream>>>(bufA, W2, dinv, bufT, n);
  spmm_relu<<<nbSp, 256, 0, stream>>>(rp, col, bufT, dinv, b2, bufA, n);
  // layer 3: 64 -> 64
  gemm_xw<64><<<nbN, 256, 0, stream>>>(bufA, W3, dinv, bufT, n);
  spmm_relu<<<nbSp, 256, 0, stream>>>(rp, col, bufT, dinv, b3, bufA, n);
  // head
  mlp_head<<<nbN, 256, 0, stream>>>(bufA, Wp1, bp1, Wp2, bp2, out, n);
}

// Round 3
// 592.989 us; speedup vs baseline: 1.0913x; 1.0913x over previous
//
#include <hip/hip_runtime.h>
#include <hip/hip_bf16.h>

#define NDIM_IN 128
#define HID 64
#define NS 8  // dst-space slices == XCD count; blockIdx%8 co-locates per XCD

// ---------------------------------------------------------------------------
// Sliced degree count: block b owns dst slice (b % NS); scans edge chunk
// (b / NS). Atomics on cnt stay XCD-local -> no cross-XCD line bouncing.
// ---------------------------------------------------------------------------
__global__ __launch_bounds__(256) void count_deg(const int* __restrict__ dst,
                                                 int* __restrict__ cnt, int E,
                                                 int slice_sz, int nchunks) {
  int s = blockIdx.x % NS;
  int c = blockIdx.x / NS;
  int lo = s * slice_sz, hi = lo + slice_sz;
  int chunk = (E + nchunks - 1) / nchunks;
  int beg = c * chunk;
  int end = min(E, beg + chunk);
  for (int i = beg + (int)threadIdx.x; i < end; i += 256) {
    int d = dst[i];
    if (d >= lo && d < hi) atomicAdd(&cnt[d], 1);
  }
}

__global__ __launch_bounds__(256) void make_dinv(const int* __restrict__ cnt,
                                                 float* __restrict__ dinv, int n) {
  int i = blockIdx.x * 256 + threadIdx.x;
  if (i < n) dinv[i] = rsqrtf((float)cnt[i] + 1.0f);  // +1 = self loop
}

// ---------------------------------------------------------------------------
// Exclusive scan of cnt -> rowptr (3-kernel hierarchical scan, n <= 512*256)
// ---------------------------------------------------------------------------
__global__ __launch_bounds__(256) void scan1(const int* __restrict__ cnt,
                                             int* __restrict__ rp,
                                             int* __restrict__ bs, int n) {
  __shared__ int s[256];
  int t = threadIdx.x;
  int i = blockIdx.x * 256 + t;
  int v = (i < n) ? cnt[i] : 0;
  s[t] = v;
  __syncthreads();
  for (int off = 1; off < 256; off <<= 1) {
    int x = (t >= off) ? s[t - off] : 0;
    __syncthreads();
    s[t] += x;
    __syncthreads();
  }
  if (i < n) rp[i] = s[t] - v;
  if (t == 255) bs[blockIdx.x] = s[255];
}

__global__ __launch_bounds__(512) void scan2(int* __restrict__ bs, int nb) {
  __shared__ int s[512];
  int t = threadIdx.x;
  int v = (t < nb) ? bs[t] : 0;
  s[t] = v;
  __syncthreads();
  for (int off = 1; off < 512; off <<= 1) {
    int x = (t >= off) ? s[t - off] : 0;
    __syncthreads();
    s[t] += x;
    __syncthreads();
  }
  if (t < nb) bs[t] = s[t] - v;
}

__global__ __launch_bounds__(256) void scan3(int* __restrict__ rp,
                                             const int* __restrict__ boff,
                                             int* __restrict__ pos, int n, int E) {
  int i = blockIdx.x * 256 + threadIdx.x;
  if (i < n) {
    int v = rp[i] + boff[blockIdx.x];
    rp[i] = v;
    pos[i] = v;
  }
  if (i == 0) rp[n] = E;
}

// ---------------------------------------------------------------------------
// Sliced CSR fill: block b owns dst slice (b % NS), scans edge chunk (b / NS).
// pos cursors + col output lines for a slice live in ONE XCD's L2.
// Sibling blocks (same chunk, 8 slices) co-reside -> chunk re-reads hit LLC.
// ---------------------------------------------------------------------------
__global__ __launch_bounds__(256) void fill_csr(const int* __restrict__ src,
                                                const int* __restrict__ dst,
                                                int* __restrict__ pos,
                                                int* __restrict__ col, int E,
                                                int slice_sz, int nchunks) {
  int s = blockIdx.x % NS;
  int c = blockIdx.x / NS;
  int lo = s * slice_sz, hi = lo + slice_sz;
  int chunk = (E + nchunks - 1) / nchunks;
  int beg = c * chunk;
  int end = min(E, beg + chunk);
  for (int i = beg + (int)threadIdx.x; i < end; i += 256) {
    int d = dst[i];
    if (d >= lo && d < hi) {
      int p = atomicAdd(&pos[d], 1);
      col[p] = src[i];
    }
  }
}

// ---------------------------------------------------------------------------
// Dense transform T' = (X @ W) * dinv[row]  (K in {64,128}), thread-per-node
// dinv fold: msg(s->d) = T[s]*dinv[s]*dinv[d]  =>  agg[d] = dinv[d]*Σ T'[col]
// ---------------------------------------------------------------------------
template <int K>
__global__ __launch_bounds__(256) void gemm_xw(const float* __restrict__ X,
                                               const float* __restrict__ W,
                                               const float* __restrict__ dinv,
                                               float* __restrict__ T, int n) {
  __shared__ float Ws[K * 64];
  for (int i = threadIdx.x; i < K * 64; i += 256) Ws[i] = W[i];
  __syncthreads();
  int node = blockIdx.x * 256 + threadIdx.x;
  if (node >= n) return;
  float4 acc[16];
#pragma unroll
  for (int j = 0; j < 16; j++) acc[j] = make_float4(0.f, 0.f, 0.f, 0.f);
  const float4* __restrict__ xr = (const float4*)(X + (size_t)node * K);
#pragma unroll
  for (int kc = 0; kc < K / 4; kc++) {
    float4 xv = xr[kc];
    float xs[4] = {xv.x, xv.y, xv.z, xv.w};
#pragma unroll
    for (int kk = 0; kk < 4; kk++) {
      float xk = xs[kk];
      const float4* wr = (const float4*)(Ws + (kc * 4 + kk) * 64);
#pragma unroll
      for (int j = 0; j < 16; j++) {
        float4 w = wr[j];
        acc[j].x += xk * w.x;
        acc[j].y += xk * w.y;
        acc[j].z += xk * w.z;
        acc[j].w += xk * w.w;
      }
    }
  }
  float di = dinv[node];
  float4* __restrict__ o = (float4*)(T + (size_t)node * 64);
#pragma unroll
  for (int j = 0; j < 16; j++) {
    acc[j].x *= di; acc[j].y *= di; acc[j].z *= di; acc[j].w *= di;
    o[j] = acc[j];
  }
}

// ---------------------------------------------------------------------------
// SpMM gather: H[v] = relu( dinv[v]*(T'[v] + Σ_{e in CSR(v)} T'[col[e]]) + b )
// wave-per-node, lane = feature (HID==64==wavefront)
// ---------------------------------------------------------------------------
__global__ __launch_bounds__(256) void spmm_relu(const int* __restrict__ rp,
                                                 const int* __restrict__ col,
                                                 const float* __restrict__ T,
                                                 const float* __restrict__ dinv,
                                                 const float* __restrict__ bias,
                                                 float* __restrict__ H, int n) {
  int gid = blockIdx.x * 256 + threadIdx.x;
  int v = gid >> 6;
  int lane = gid & 63;
  if (v >= n) return;
  int beg = rp[v], end = rp[v + 1];
  float acc0 = T[(size_t)v * HID + lane];  // self loop (dinv[v] applied at end)
  float acc1 = 0.f, acc2 = 0.f, acc3 = 0.f;
  int e = beg;
  for (; e + 4 <= end; e += 4) {
    int s0 = col[e], s1 = col[e + 1], s2 = col[e + 2], s3 = col[e + 3];
    acc0 += T[(size_t)s0 * HID + lane];
    acc1 += T[(size_t)s1 * HID + lane];
    acc2 += T[(size_t)s2 * HID + lane];
    acc3 += T[(size_t)s3 * HID + lane];
  }
  for (; e < end; e++) acc0 += T[(size_t)col[e] * HID + lane];
  float r = dinv[v] * (acc0 + acc1 + acc2 + acc3) + bias[lane];
  H[(size_t)v * HID + lane] = r > 0.f ? r : 0.f;
}

// ---------------------------------------------------------------------------
// Fused MLP head: out = relu(H @ Wp1 + bp1) @ Wp2 + bp2, thread-per-node
// ---------------------------------------------------------------------------
__global__ __launch_bounds__(256) void mlp_head(const float* __restrict__ H,
                                                const float* __restrict__ Wp1,
                                                const float* __restrict__ bp1,
                                                const float* __restrict__ Wp2,
                                                const float* __restrict__ bp2,
                                                float* __restrict__ out, int n) {
  __shared__ float W1t[32 * 64];  // transposed: W1t[j*64+k] = Wp1[k*32+j]
  __shared__ float w2s[32];
  __shared__ float b1s[32];
  for (int i = threadIdx.x; i < 64 * 32; i += 256) {
    int k = i >> 5, j = i & 31;
    W1t[j * 64 + k] = Wp1[i];
  }
  if (threadIdx.x < 32) {
    w2s[threadIdx.x] = Wp2[threadIdx.x];
    b1s[threadIdx.x] = bp1[threadIdx.x];
  }
  __syncthreads();
  int node = blockIdx.x * 256 + threadIdx.x;
  if (node >= n) return;
  float4 h[16];
  const float4* __restrict__ hr = (const float4*)(H + (size_t)node * 64);
#pragma unroll
  for (int j = 0; j < 16; j++) h[j] = hr[j];
  float o = bp2[0];
#pragma unroll
  for (int j = 0; j < 32; j++) {
    const float4* wr = (const float4*)(W1t + j * 64);
    float4 a4 = make_float4(0.f, 0.f, 0.f, 0.f);
#pragma unroll
    for (int k = 0; k < 16; k++) {
      float4 w = wr[k];
      a4.x += h[k].x * w.x;
      a4.y += h[k].y * w.y;
      a4.z += h[k].z * w.z;
      a4.w += h[k].w * w.w;
    }
    float a = a4.x + a4.y + a4.z + a4.w + b1s[j];
    a = a > 0.f ? a : 0.f;
    o += a * w2s[j];
  }
  out[node] = o;
}

// ---------------------------------------------------------------------------
extern "C" void kernel_launch(void* const* d_in, const int* in_sizes, int n_in,
                              void* d_out, int out_size, void* d_ws, size_t ws_size,
                              hipStream_t stream) {
  const float* x   = (const float*)d_in[0];
  const int* edge  = (const int*)d_in[1];
  const float* W1  = (const float*)d_in[3];
  const float* b1  = (const float*)d_in[4];
  const float* W2  = (const float*)d_in[5];
  const float* b2  = (const float*)d_in[6];
  const float* W3  = (const float*)d_in[7];
  const float* b3  = (const float*)d_in[8];
  const float* Wp1 = (const float*)d_in[9];
  const float* bp1 = (const float*)d_in[10];
  const float* Wp2 = (const float*)d_in[11];
  const float* bp2 = (const float*)d_in[12];
  float* out = (float*)d_out;

  const int n = in_sizes[0] / NDIM_IN;   // 100000
  const int E = in_sizes[1] / 2;         // 1600000
  const int* src = edge;
  const int* dst = edge + E;

  // workspace carve-out (256B aligned slices)
  char* ws = (char*)d_ws;
  size_t off = 0;
  auto carve = [&](size_t bytes) {
    char* p = ws + off;
    off = (off + bytes + 255) & ~(size_t)255;
    return p;
  };
  int*   cnt   = (int*)carve((size_t)n * 4);
  float* dinv  = (float*)carve((size_t)n * 4);
  int*   rp    = (int*)carve(((size_t)n + 1) * 4);
  int*   pos   = (int*)carve((size_t)n * 4);
  int*   bsum  = (int*)carve(512 * 4);
  int*   col   = (int*)carve((size_t)E * 4);
  float* bufT  = (float*)carve((size_t)n * HID * 4);
  float* bufA  = (float*)carve((size_t)n * HID * 4);
  (void)ws_size; (void)n_in; (void)out_size;

  const int nbN = (n + 255) / 256;       // 391 (<=512 for scan2)
  const int slice_sz = (n + NS - 1) / NS;  // 12500
  const int nchunks = 128;               // 8*128 = 1024 blocks for sliced kernels

  hipMemsetAsync(cnt, 0, (size_t)n * 4, stream);
  count_deg<<<NS * nchunks, 256, 0, stream>>>(dst, cnt, E, slice_sz, nchunks);
  make_dinv<<<nbN, 256, 0, stream>>>(cnt, dinv, n);
  scan1<<<nbN, 256, 0, stream>>>(cnt, rp, bsum, n);
  scan2<<<1, 512, 0, stream>>>(bsum, nbN);
  scan3<<<nbN, 256, 0, stream>>>(rp, bsum, pos, n, E);
  fill_csr<<<NS * nchunks, 256, 0, stream>>>(src, dst, pos, col, E, slice_sz, nchunks);

  const int nbSp = ((n * 64) + 255) / 256;

  // layer 1: 128 -> 64
  gemm_xw<128><<<nbN, 256, 0, stream>>>(x, W1, dinv, bufT, n);
  spmm_relu<<<nbSp, 256, 0, stream>>>(rp, col, bufT, dinv, b1, bufA, n);
  // layer 2: 64 -> 64
  gemm_xw<64><<<nbN, 256, 0, stream>>>(bufA, W2, dinv, bufT, n);
  spmm_relu<<<nbSp, 256, 0, stream>>>(rp, col, bufT, dinv, b2, bufA, n);
  // layer 3: 64 -> 64
  gemm_xw<64><<<nbN, 256, 0, stream>>>(bufA, W3, dinv, bufT, n);
  spmm_relu<<<nbSp, 256, 0, stream>>>(rp, col, bufT, dinv, b3, bufA, n);
  // head
  mlp_head<<<nbN, 256, 0, stream>>>(bufA, Wp1, bp1, Wp2, bp2, out, n);
}